// Round 1
// baseline (525.883 us; speedup 1.0000x reference)
//
#include <hip/hip_runtime.h>
#include <hip/hip_bf16.h>
#include <math.h>

#define T_TOKENS 16384
#define H_DIM    4096
#define N_EXP    64
#define KSPLIT   4
#define KCHUNK   (H_DIM / KSPLIT)   // 1024
#define MTILE    128
#define BK       32
#define NB       128                // hist/scatter chunks of 256 elements

// ---------------- Kernel 1: gate GEMM, fp32, K-split partials ----------------
// grid = (T/MTILE) * KSPLIT = 128*4 = 512 blocks, 256 threads.
// Thread-tile 8 tokens x 4 experts. part[kc][tok][e] written exclusively.
__global__ __launch_bounds__(256, 2)
void gate_gemm(const float* __restrict__ x, const float* __restrict__ W,
               float* __restrict__ part) {
  __shared__ float xs[MTILE][BK + 1];
  __shared__ float wsm[N_EXP][BK + 1];
  const int bx = blockIdx.x;
  const int kc = bx >> 7;            // 0..3
  const int tb = (bx & 127) * MTILE; // token base
  const int t  = threadIdx.x;
  const int tokgrp = t & 15;         // 16 groups of 8 tokens
  const int expgrp = t >> 4;         // 16 groups of 4 experts
  const int lrow = t >> 3;           // staging row (0..31)
  const int lcol = (t & 7) * 4;      // staging col
  const int k0 = kc * KCHUNK;

  float acc[8][4];
  #pragma unroll
  for (int i = 0; i < 8; ++i)
    #pragma unroll
    for (int j = 0; j < 4; ++j) acc[i][j] = 0.f;

  for (int kb = 0; kb < KCHUNK; kb += BK) {
    __syncthreads();
    // stage x tile: 128 rows x 32 cols
    #pragma unroll
    for (int r = 0; r < 4; ++r) {
      const int row = lrow + 32 * r;
      const float4 v = *reinterpret_cast<const float4*>(
          &x[(size_t)(tb + row) * H_DIM + k0 + kb + lcol]);
      xs[row][lcol + 0] = v.x; xs[row][lcol + 1] = v.y;
      xs[row][lcol + 2] = v.z; xs[row][lcol + 3] = v.w;
    }
    // stage W tile: 64 rows x 32 cols
    #pragma unroll
    for (int r = 0; r < 2; ++r) {
      const int row = lrow + 32 * r;
      const float4 v = *reinterpret_cast<const float4*>(
          &W[(size_t)row * H_DIM + k0 + kb + lcol]);
      wsm[row][lcol + 0] = v.x; wsm[row][lcol + 1] = v.y;
      wsm[row][lcol + 2] = v.z; wsm[row][lcol + 3] = v.w;
    }
    __syncthreads();
    #pragma unroll 8
    for (int kk = 0; kk < BK; ++kk) {
      float xa[8], wa[4];
      #pragma unroll
      for (int i = 0; i < 8; ++i) xa[i] = xs[tokgrp * 8 + i][kk];
      #pragma unroll
      for (int j = 0; j < 4; ++j) wa[j] = wsm[expgrp * 4 + j][kk];
      #pragma unroll
      for (int i = 0; i < 8; ++i)
        #pragma unroll
        for (int j = 0; j < 4; ++j)
          acc[i][j] = fmaf(xa[i], wa[j], acc[i][j]);
    }
  }
  float* dst = part + (size_t)kc * T_TOKENS * N_EXP;
  #pragma unroll
  for (int i = 0; i < 8; ++i) {
    const int tok = tb + tokgrp * 8 + i;
    float4 v = make_float4(acc[i][0], acc[i][1], acc[i][2], acc[i][3]);
    *reinterpret_cast<float4*>(&dst[(size_t)tok * N_EXP + expgrp * 4]) = v;
  }
}

// ---------------- Kernel 2: softmax + top-2 + renorm (1 wave / token) --------
__global__ __launch_bounds__(256)
void softmax_top2(const float* __restrict__ part, float* __restrict__ out,
                  int* __restrict__ sel) {
  const int lane = threadIdx.x & 63;               // lane = expert
  const int tok  = blockIdx.x * 4 + (threadIdx.x >> 6);
  const size_t base = (size_t)tok * N_EXP + lane;
  float l = 0.f;
  #pragma unroll
  for (int c = 0; c < KSPLIT; ++c)                 // fixed summation order
    l += part[(size_t)c * T_TOKENS * N_EXP + base];
  // softmax
  float m = l;
  #pragma unroll
  for (int o = 32; o >= 1; o >>= 1) m = fmaxf(m, __shfl_xor(m, o));
  const float e = expf(l - m);
  float s = e;
  #pragma unroll
  for (int o = 32; o >= 1; o >>= 1) s += __shfl_xor(s, o);
  const float p = e / s;
  // top-1 (tie -> lowest index, matching lax.top_k)
  float v1 = p; int i1 = lane;
  #pragma unroll
  for (int o = 32; o >= 1; o >>= 1) {
    const float ov = __shfl_xor(v1, o); const int oi = __shfl_xor(i1, o);
    if (ov > v1 || (ov == v1 && oi < i1)) { v1 = ov; i1 = oi; }
  }
  // top-2: exclude the top-1 element
  float v2 = (lane == i1) ? -INFINITY : p; int i2 = lane;
  #pragma unroll
  for (int o = 32; o >= 1; o >>= 1) {
    const float ov = __shfl_xor(v2, o); const int oi = __shfl_xor(i2, o);
    if (ov > v2 || (ov == v2 && oi < i2)) { v2 = ov; i2 = oi; }
  }
  if (lane == 0) {
    const float den = v1 + v2;
    out[2 * tok]     = v1 / den;
    out[2 * tok + 1] = v2 / den;
    out[2 * T_TOKENS + 2 * tok]     = (float)i1;
    out[2 * T_TOKENS + 2 * tok + 1] = (float)i2;
    sel[2 * tok]     = i1;
    sel[2 * tok + 1] = i2;
  }
}

// ---------------- Kernel 3: per-chunk histogram (chunk = 256 assignments) ----
__global__ __launch_bounds__(256)
void hist_kernel(const int* __restrict__ sel, int* __restrict__ hist) {
  __shared__ int h[N_EXP];
  const int t = threadIdx.x;
  if (t < N_EXP) h[t] = 0;
  __syncthreads();
  atomicAdd(&h[sel[blockIdx.x * 256 + t]], 1);
  __syncthreads();
  if (t < N_EXP) hist[blockIdx.x * N_EXP + t] = h[t];
}

// ---------------- Kernel 4: expert totals + bases + per-chunk offsets --------
__global__ __launch_bounds__(64)
void scan_kernel(const int* __restrict__ hist, int* __restrict__ boff,
                 float* __restrict__ out_msizes) {
  const int e = threadIdx.x;   // 64 threads, lane = expert
  int total = 0;
  for (int b = 0; b < NB; ++b) total += hist[b * N_EXP + e];
  out_msizes[e] = (float)total;
  // exclusive scan across experts (single wave)
  int incl = total;
  #pragma unroll
  for (int o = 1; o < 64; o <<= 1) {
    const int v = __shfl_up(incl, o);
    if (e >= o) incl += v;
  }
  int run = incl - total;      // exclusive base for expert e
  for (int b = 0; b < NB; ++b) {
    boff[b * N_EXP + e] = run;
    run += hist[b * N_EXP + e];
  }
}

// ---------------- Kernel 5: stable scatter (counting-sort permutation) -------
__global__ __launch_bounds__(256)
void scatter_kernel(const int* __restrict__ sel, const int* __restrict__ boff,
                    float* __restrict__ out_gather) {
  __shared__ int le[256];
  __shared__ int off[N_EXP];
  const int t = threadIdx.x;
  const int i = blockIdx.x * 256 + t;   // flat assignment index
  const int e = sel[i];
  le[t] = e;
  if (t < N_EXP) off[t] = boff[blockIdx.x * N_EXP + t];
  __syncthreads();
  int rank = 0;
  for (int j = 0; j < 256; ++j)          // LDS broadcast reads
    rank += (j < t) & (le[j] == e);
  out_gather[off[e] + rank] = (float)i;
}

// ---------------- Launch ----------------
extern "C" void kernel_launch(void* const* d_in, const int* in_sizes, int n_in,
                              void* d_out, int out_size, void* d_ws, size_t ws_size,
                              hipStream_t stream) {
  const float* x = (const float*)d_in[0];   // (16384, 4096)
  const float* W = (const float*)d_in[1];   // (64, 4096)
  float* out = (float*)d_out;               // [weights 32768][sel 32768][m 64][gather 32768]

  // workspace layout (~16.2 MiB)
  float* part = (float*)d_ws;                                    // KSPLIT*T*E fp32
  int*   sel  = (int*)(part + (size_t)KSPLIT * T_TOKENS * N_EXP);// 32768 ints
  int*   hist = sel + 2 * T_TOKENS;                              // NB*64 ints
  int*   boff = hist + NB * N_EXP;                               // NB*64 ints

  hipLaunchKernelGGL(gate_gemm, dim3((T_TOKENS / MTILE) * KSPLIT), dim3(256), 0, stream,
                     x, W, part);
  hipLaunchKernelGGL(softmax_top2, dim3(T_TOKENS / 4), dim3(256), 0, stream,
                     part, out, sel);
  hipLaunchKernelGGL(hist_kernel, dim3(NB), dim3(256), 0, stream, sel, hist);
  hipLaunchKernelGGL(scan_kernel, dim3(1), dim3(64), 0, stream,
                     boff ? hist : hist, boff, out + 4 * T_TOKENS);
  hipLaunchKernelGGL(scatter_kernel, dim3(NB), dim3(256), 0, stream,
                     sel, boff, out + 4 * T_TOKENS + N_EXP);
}